// Round 6
// baseline (251.542 us; speedup 1.0000x reference)
//
#include <hip/hip_runtime.h>

typedef short bf16x8 __attribute__((ext_vector_type(8)));
typedef float f32x4 __attribute__((ext_vector_type(4)));

// Problem constants (fixed by reference setup_inputs)
constexpr int Bc = 4;
constexpr int Nc = 50000;
constexpr int Kc = 10;
constexpr int Fc = 128;
constexpr int Hc = 16;
constexpr int Cc = 64;            // 4*H output channels
constexpr int NODES = Bc * Nc;    // 200000
constexpr int NPB = 8;            // nodes per tile
constexpr int ROWS = NPB * Kc;    // 80 GEMM rows per tile
constexpr int MT = ROWS / 16;     // 5 M-tiles
constexpr int BLK = 256;          // 4 waves (N-split: wave w owns cols 16w..16w+15)
constexpr int NTILES = NODES / NPB;  // 25000
constexpr int NBLK = 1024;        // persistent blocks: 4 per CU

// LDS (phases alias):
//  stage/MFMA: xl bf16 [80 rows][256 B], XOR-swizzled      bytes [0, 20480)
//  post:       hw f32 [80][68] bytes [0,21760) ; ol f32 [8][68] bytes [21760,23936)
constexpr int LDS_BYTES = 23936;
constexpr int OL_OFF = 21760;

__device__ __forceinline__ unsigned short f2bf(float f) {
    // round-to-nearest-even fp32 -> bf16
    unsigned u = __builtin_bit_cast(unsigned, f);
    return (unsigned short)((u + 0x7fffu + ((u >> 16) & 1u)) >> 16);
}

// raw barrier: order LDS only (lgkmcnt), never drain vmcnt -> prefetch loads
// stay in flight across it (m201 pattern; sched_barrier per rule #18)
__device__ __forceinline__ void bar_lds() {
    asm volatile("s_waitcnt lgkmcnt(0)" ::: "memory");
    __builtin_amdgcn_sched_barrier(0);
    __builtin_amdgcn_s_barrier();
    __builtin_amdgcn_sched_barrier(0);
}

// Prep: W [128][64] f32 -> per-lane B-fragment image in d_ws (bf16).
// dst = w*2048 + l*32 + kc*8 + j  <->  c = w*16 + (l&15), f = kc*32 + (l>>4)*8 + j.
__global__ __launch_bounds__(256)
void prep_w(const float* __restrict__ W, unsigned short* __restrict__ wt) {
    const int dst = blockIdx.x * 256 + threadIdx.x;   // 8192 total
    const int j  = dst & 7;
    const int kc = (dst >> 3) & 3;
    const int l  = (dst >> 5) & 63;
    const int w  = dst >> 11;
    const int c  = w * 16 + (l & 15);
    const int f  = kc * 32 + (l >> 4) * 8 + j;
    wt[dst] = f2bf(W[f * 64 + c]);
}

__global__ __launch_bounds__(BLK, 4)
void gat_kernel(const float* __restrict__ x,
                const unsigned short* __restrict__ wt_ws,
                const float* __restrict__ a,
                float* __restrict__ out)
{
    __shared__ __align__(16) char smem[LDS_BYTES];

    const int t  = threadIdx.x;
    const int w  = t >> 6;    // wave -> col-tile
    const int l  = t & 63;
    const int lr = l & 15;    // A-row / B-col within tile
    const int lk = l >> 4;    // k sub-block (8 contiguous k)

    // B fragments: 64 contiguous bytes per lane from the prepped image (L2-hit), once
    bf16x8 bfrag[4];
    {
        const bf16x8* wp = reinterpret_cast<const bf16x8*>(wt_ws + w * 2048 + l * 32);
#pragma unroll
        for (int kc = 0; kc < 4; ++kc) bfrag[kc] = wp[kc];
    }

    // attention coefficients (softmax thread role: h = t&15), hoisted out of the loop
    const float ar0 = a[0 * Hc + (t & 15)];
    const float ar1 = a[1 * Hc + (t & 15)];
    const float ar2 = a[2 * Hc + (t & 15)];
    const float ar3 = a[3 * Hc + (t & 15)];

    // ---- prologue: load tile 0 into staging regs ----
    int tile = blockIdx.x;
    float4 st[10];
    {
        const float* xg = x + (size_t)tile * (ROWS * Fc);
#pragma unroll
        for (int i = 0; i < 5; ++i) {
            st[2 * i]     = *reinterpret_cast<const float4*>(xg + i * 2048 + t * 8);
            st[2 * i + 1] = *reinterpret_cast<const float4*>(xg + i * 2048 + t * 8 + 4);
        }
    }

    for (;;) {
        // ---- phase 0: cvt + ds_write staged regs -> xl (swizzled) ----
#pragma unroll
        for (int i = 0; i < 5; ++i) {
            const float4 v0 = st[2 * i];
            const float4 v1 = st[2 * i + 1];
            const int row = i * 16 + (t >> 4);
            const int byt = ((t & 15) * 16) ^ ((row & 7) << 4);
            uint4 p;
            p.x = (unsigned)f2bf(v0.x) | ((unsigned)f2bf(v0.y) << 16);
            p.y = (unsigned)f2bf(v0.z) | ((unsigned)f2bf(v0.w) << 16);
            p.z = (unsigned)f2bf(v1.x) | ((unsigned)f2bf(v1.y) << 16);
            p.w = (unsigned)f2bf(v1.z) | ((unsigned)f2bf(v1.w) << 16);
            *reinterpret_cast<uint4*>(smem + row * 256 + byt) = p;
        }
        bar_lds();

        // ---- phase 1: issue next tile's global loads (fly across MFMA/softmax) ----
        const int ntile = tile + NBLK;
        if (ntile < NTILES) {
            const float* xg = x + (size_t)ntile * (ROWS * Fc);
#pragma unroll
            for (int i = 0; i < 5; ++i) {
                st[2 * i]     = *reinterpret_cast<const float4*>(xg + i * 2048 + t * 8);
                st[2 * i + 1] = *reinterpret_cast<const float4*>(xg + i * 2048 + t * 8 + 4);
            }
        }

        // ---- phase 2: MFMA  hw[80][64] = x_bf16 . Wt^T ----
        f32x4 acc[MT];
#pragma unroll
        for (int m = 0; m < MT; ++m) acc[m] = (f32x4){0.f, 0.f, 0.f, 0.f};
#pragma unroll
        for (int m = 0; m < MT; ++m) {
            const int row = m * 16 + lr;
            const char* xrow = smem + row * 256;
            const int sw = (row & 7) << 4;
#pragma unroll
            for (int kc = 0; kc < 4; ++kc) {
                const bf16x8 af = *reinterpret_cast<const bf16x8*>(xrow + ((kc * 64 + lk * 16) ^ sw));
                acc[m] = __builtin_amdgcn_mfma_f32_16x16x32_bf16(af, bfrag[kc], acc[m], 0, 0, 0);
            }
        }
        bar_lds();   // xl dead beyond this point (hw aliases it); loads stay in flight

        // ---- phase 3: acc -> hw LDS [80][68] (D-frag: row = lk*4+r, col = lr) ----
        {
            float* hw = reinterpret_cast<float*>(smem);
            const int col = w * 16 + lr;
#pragma unroll
            for (int m = 0; m < MT; ++m) {
                const int rbase = m * 16 + lk * 4;
#pragma unroll
                for (int r = 0; r < 4; ++r)
                    hw[(rbase + r) * 68 + col] = acc[m][r];
            }
        }
        bar_lds();

        // ---- phase 4: softmax over K=10 + leaky relu, thread = (node, head) ----
        {
            const float* hw = reinterpret_cast<const float*>(smem);
            float* ol = reinterpret_cast<float*>(smem + OL_OFF);
            if (t < NPB * Hc) {   // 128 active
                const int ln = t >> 4;
                float4 hv[Kc];
                float  lg[Kc];
                float  mx = -1e30f;
#pragma unroll
                for (int k = 0; k < Kc; ++k) {
                    hv[k] = *reinterpret_cast<const float4*>(hw + (ln * Kc + k) * 68 + (t & 15) * 4);
                    lg[k] = fmaf(hv[k].x, ar0, fmaf(hv[k].y, ar1, fmaf(hv[k].z, ar2, hv[k].w * ar3)));
                    mx = fmaxf(mx, lg[k]);
                }
                float lsum = 0.f, o0 = 0.f, o1 = 0.f, o2 = 0.f, o3 = 0.f;
#pragma unroll
                for (int k = 0; k < Kc; ++k) {
                    const float p = __expf(lg[k] - mx);
                    lsum += p;
                    o0 = fmaf(p, hv[k].x, o0);
                    o1 = fmaf(p, hv[k].y, o1);
                    o2 = fmaf(p, hv[k].z, o2);
                    o3 = fmaf(p, hv[k].w, o3);
                }
                const float inv = 1.f / lsum;
                o0 *= inv; o1 *= inv; o2 *= inv; o3 *= inv;
                o0 = fmaxf(o0, 0.2f * o0);   // leaky_relu slope 0.2
                o1 = fmaxf(o1, 0.2f * o1);
                o2 = fmaxf(o2, 0.2f * o2);
                o3 = fmaxf(o3, 0.2f * o3);
                *reinterpret_cast<float4*>(ol + ln * 68 + (t & 15) * 4) = make_float4(o0, o1, o2, o3);
            }
        }
        bar_lds();   // all softmax hw-reads done -> next ds_write may clobber hw

        // ---- phase 5: store transposed [B, 64, N], coalesced float4 ----
        if (t < 128) {
            const float* ol = reinterpret_cast<const float*>(smem + OL_OFF);
            const int c  = t >> 1;   // channel 0..63
            const int nq = t & 1;    // node quad 0..1
            const int nb = tile * NPB;
            const int b  = nb / Nc;
            const int n0 = nb - b * Nc;
            float4 v;
            v.x = ol[(nq * 4 + 0) * 68 + c];
            v.y = ol[(nq * 4 + 1) * 68 + c];
            v.z = ol[(nq * 4 + 2) * 68 + c];
            v.w = ol[(nq * 4 + 3) * 68 + c];
            *reinterpret_cast<float4*>(out + ((size_t)b * Cc + c) * Nc + n0 + nq * 4) = v;
        }

        tile = ntile;
        if (tile >= NTILES) break;
        // note: no barrier needed here — phase-0 ds_writes touch [0,20480) only
        // (hw region, dead after phase-4 barrier); ol [21760+) read by phase 5 is untouched.
    }
}

extern "C" void kernel_launch(void* const* d_in, const int* in_sizes, int n_in,
                              void* d_out, int out_size, void* d_ws, size_t ws_size,
                              hipStream_t stream) {
    const float* x = (const float*)d_in[0];
    const float* W = (const float*)d_in[1];
    const float* a = (const float*)d_in[2];
    float* out = (float*)d_out;
    unsigned short* wt = (unsigned short*)d_ws;   // 16 KB used

    prep_w<<<32, 256, 0, stream>>>(W, wt);
    gat_kernel<<<NBLK, BLK, 0, stream>>>(x, wt, a, out);
}

// Round 7
// 236.891 us; speedup vs baseline: 1.0618x; 1.0618x over previous
//
#include <hip/hip_runtime.h>

typedef short bf16x8 __attribute__((ext_vector_type(8)));
typedef float f32x4 __attribute__((ext_vector_type(4)));

// Problem constants (fixed by reference setup_inputs)
constexpr int Bc = 4;
constexpr int Nc = 50000;
constexpr int Kc = 10;
constexpr int Fc = 128;
constexpr int Hc = 16;
constexpr int Cc = 64;            // 4*H output channels
constexpr int NODES = Bc * Nc;    // 200000
constexpr int NPB = 8;            // nodes per block
constexpr int ROWS = NPB * Kc;    // 80 GEMM rows per block
constexpr int MT = ROWS / 16;     // 5 M-tiles
constexpr int BLK = 256;          // 4 waves (N-split: wave w owns cols 16w..16w+15)
constexpr int NTILES = NODES / NPB;  // 25000

// LDS (phases alias):
//  stage/MFMA: xl bf16 [80 rows][256 B], XOR-swizzled   bytes [0, 20480)
//  post:       hw f32 [80][64] (aliases xl)             bytes [0, 20480)
//              ol f32 [8][64]                           bytes [20480, 22528)
constexpr int OL_OFF = 20480;
constexpr int LDS_BYTES = 22528;   // 7 blocks/CU

__device__ __forceinline__ unsigned short f2bf(float f) {
    // round-to-nearest-even fp32 -> bf16 (prep kernel only)
    unsigned u = __builtin_bit_cast(unsigned, f);
    return (unsigned short)((u + 0x7fffu + ((u >> 16) & 1u)) >> 16);
}

__device__ __forceinline__ unsigned cvtpk(float lo, float hi) {
    // packed RNE fp32->bf16: D[15:0]=bf16(lo), D[31:16]=bf16(hi)
    unsigned r;
    asm("v_cvt_pk_bf16_f32 %0, %1, %2" : "=v"(r) : "v"(lo), "v"(hi));
    return r;
}

// Prep: W [128][64] f32 -> per-lane B-fragment image in d_ws (bf16).
// dst = w*2048 + l*32 + kc*8 + j  <->  c = w*16 + (l&15), f = kc*32 + (l>>4)*8 + j.
__global__ __launch_bounds__(256)
void prep_w(const float* __restrict__ W, unsigned short* __restrict__ wt) {
    const int dst = blockIdx.x * 256 + threadIdx.x;   // 8192 total
    const int j  = dst & 7;
    const int kc = (dst >> 3) & 3;
    const int l  = (dst >> 5) & 63;
    const int w  = dst >> 11;
    const int c  = w * 16 + (l & 15);
    const int f  = kc * 32 + (l >> 4) * 8 + j;
    wt[dst] = f2bf(W[f * 64 + c]);
}

__global__ __launch_bounds__(BLK, 8)
void gat_kernel(const float* __restrict__ x,
                const unsigned short* __restrict__ wt_ws,
                const float* __restrict__ a,
                float* __restrict__ out)
{
    __shared__ __align__(16) char smem[LDS_BYTES];

    const int t  = threadIdx.x;
    const int w  = t >> 6;    // wave -> col-tile
    const int l  = t & 63;
    const int lr = l & 15;    // A-row / B-col within tile
    const int lk = l >> 4;    // k sub-block (8 contiguous k)

    // ---- phase A: stage x fp32 -> bf16 into LDS, swizzled; low-pressure loop ----
    {
        const float* xg = x + (size_t)blockIdx.x * (ROWS * Fc);
        const int r0 = t >> 4;                       // row within 16-row group
        const int sw = (r0 & 7) << 4;                // loop-invariant (16 == 0 mod 8)
        char* wr = smem + r0 * 256 + (((t & 15) * 16) ^ sw);
#pragma unroll 1
        for (int i = 0; i < 5; ++i) {
            const float4 v0 = *reinterpret_cast<const float4*>(xg + i * 2048 + t * 8);
            const float4 v1 = *reinterpret_cast<const float4*>(xg + i * 2048 + t * 8 + 4);
            uint4 p;
            p.x = cvtpk(v0.x, v0.y);
            p.y = cvtpk(v0.z, v0.w);
            p.z = cvtpk(v1.x, v1.y);
            p.w = cvtpk(v1.z, v1.w);
            *reinterpret_cast<uint4*>(wr + i * 4096) = p;
        }
    }

    // B fragments: 64 contiguous bytes per lane from the prepped image (L2-hit)
    bf16x8 bfrag[4];
    {
        const bf16x8* wp = reinterpret_cast<const bf16x8*>(wt_ws + w * 2048 + l * 32);
#pragma unroll
        for (int kc = 0; kc < 4; ++kc) bfrag[kc] = wp[kc];
    }
    __syncthreads();

    // ---- phase B: MFMA  hw[80][64] = x_bf16 . Wt^T ----
    f32x4 acc[MT];
#pragma unroll
    for (int m = 0; m < MT; ++m) acc[m] = (f32x4){0.f, 0.f, 0.f, 0.f};
#pragma unroll
    for (int m = 0; m < MT; ++m) {
        const char* xrow = smem + (m * 16 + lr) * 256;
        const int sw = (lr & 7) << 4;
#pragma unroll
        for (int kc = 0; kc < 4; ++kc) {
            const bf16x8 af = *reinterpret_cast<const bf16x8*>(xrow + ((kc * 64 + lk * 16) ^ sw));
            acc[m] = __builtin_amdgcn_mfma_f32_16x16x32_bf16(af, bfrag[kc], acc[m], 0, 0, 0);
        }
    }
    __syncthreads();   // xl dead beyond this point (hw aliases it)

    // ---- phase C: acc -> hw LDS [80][64] f32 (D-frag: row = lk*4+r, col = lr) ----
    {
        float* hw = reinterpret_cast<float*>(smem);
        const int col = w * 16 + lr;
#pragma unroll
        for (int m = 0; m < MT; ++m) {
            const int rbase = m * 16 + lk * 4;
#pragma unroll
            for (int r = 0; r < 4; ++r)
                hw[(rbase + r) * 64 + col] = acc[m][r];
        }
    }
    __syncthreads();

    // ---- phase D: online softmax over K=10 + leaky relu, thread = (node, head) ----
    if (t < NPB * Hc) {   // 128 active
        const int h  = t & 15;
        const int ln = t >> 4;
        const float ar0 = a[h];
        const float ar1 = a[16 + h];
        const float ar2 = a[32 + h];
        const float ar3 = a[48 + h];
        const float* hwb = reinterpret_cast<const float*>(smem) + (ln * Kc) * 64 + h * 4;

        float mx = -1e30f, lsum = 0.f;
        float o0 = 0.f, o1 = 0.f, o2 = 0.f, o3 = 0.f;
#pragma unroll
        for (int k = 0; k < Kc; ++k) {
            const float4 hv = *reinterpret_cast<const float4*>(hwb + k * 64);
            const float lg = fmaf(hv.x, ar0, fmaf(hv.y, ar1, fmaf(hv.z, ar2, hv.w * ar3)));
            const float mn = fmaxf(mx, lg);
            const float s  = __expf(mx - mn);
            const float p  = __expf(lg - mn);
            mx = mn;
            lsum = fmaf(lsum, s, p);
            o0 = fmaf(o0, s, p * hv.x);
            o1 = fmaf(o1, s, p * hv.y);
            o2 = fmaf(o2, s, p * hv.z);
            o3 = fmaf(o3, s, p * hv.w);
        }
        const float inv = 1.f / lsum;
        o0 *= inv; o1 *= inv; o2 *= inv; o3 *= inv;
        o0 = fmaxf(o0, 0.2f * o0);   // leaky_relu slope 0.2
        o1 = fmaxf(o1, 0.2f * o1);
        o2 = fmaxf(o2, 0.2f * o2);
        o3 = fmaxf(o3, 0.2f * o3);
        float* ol = reinterpret_cast<float*>(smem + OL_OFF);
        *reinterpret_cast<float4*>(ol + ln * 64 + h * 4) = make_float4(o0, o1, o2, o3);
    }
    __syncthreads();

    // ---- phase E: store transposed [B, 64, N], coalesced float4 ----
    if (t < 128) {
        const float* ol = reinterpret_cast<const float*>(smem + OL_OFF);
        const int c  = t >> 1;   // channel 0..63
        const int nq = t & 1;    // node quad 0..1
        const int nb = blockIdx.x * NPB;
        const int b  = nb / Nc;
        const int n0 = nb - b * Nc;
        float4 v;
        v.x = ol[(nq * 4 + 0) * 64 + c];
        v.y = ol[(nq * 4 + 1) * 64 + c];
        v.z = ol[(nq * 4 + 2) * 64 + c];
        v.w = ol[(nq * 4 + 3) * 64 + c];
        *reinterpret_cast<float4*>(out + ((size_t)b * Cc + c) * Nc + n0 + nq * 4) = v;
    }
}

extern "C" void kernel_launch(void* const* d_in, const int* in_sizes, int n_in,
                              void* d_out, int out_size, void* d_ws, size_t ws_size,
                              hipStream_t stream) {
    const float* x = (const float*)d_in[0];
    const float* W = (const float*)d_in[1];
    const float* a = (const float*)d_in[2];
    float* out = (float*)d_out;
    unsigned short* wt = (unsigned short*)d_ws;   // 16 KB used

    prep_w<<<32, 256, 0, stream>>>(W, wt);
    gat_kernel<<<NTILES, BLK, 0, stream>>>(x, wt, a, out);
}

// Round 8
// 228.967 us; speedup vs baseline: 1.0986x; 1.0346x over previous
//
#include <hip/hip_runtime.h>

typedef short bf16x8 __attribute__((ext_vector_type(8)));
typedef float f32x4 __attribute__((ext_vector_type(4)));

// Problem constants (fixed by reference setup_inputs)
constexpr int Bc = 4;
constexpr int Nc = 50000;
constexpr int Kc = 10;
constexpr int Fc = 128;
constexpr int Hc = 16;
constexpr int Cc = 64;            // 4*H output channels
constexpr int NODES = Bc * Nc;    // 200000
constexpr int NPB = 8;            // nodes per block
constexpr int ROWS = NPB * Kc;    // 80 GEMM rows per block
constexpr int MT = ROWS / 16;     // 5 M-tiles
constexpr int BLK = 256;          // 4 waves (N-split: wave w owns cols 16w..16w+15)
constexpr int NTILES = NODES / NPB;  // 25000

// LDS: x fp32 [80 rows][512 B], 16B-unit XOR-swizzled (unit ^= row&7)  = 40960 B
//   -> exactly 4 blocks/CU (4 x 40960 = 163840).
// After phase B the x region is dead and is aliased by:
//   hw f32 [80][68]  bytes [0, 21760) ; ol f32 [8][68] bytes [21760, 23936)
constexpr int LDS_BYTES = 40960;
constexpr int OL_OFF = 21760;

__device__ __forceinline__ unsigned short f2bf(float f) {
    // round-to-nearest-even fp32 -> bf16 (prep kernel only)
    unsigned u = __builtin_bit_cast(unsigned, f);
    return (unsigned short)((u + 0x7fffu + ((u >> 16) & 1u)) >> 16);
}

__device__ __forceinline__ unsigned cvtpk(float lo, float hi) {
    // packed RNE fp32->bf16: D[15:0]=bf16(lo), D[31:16]=bf16(hi)
    unsigned r;
    asm("v_cvt_pk_bf16_f32 %0, %1, %2" : "=v"(r) : "v"(lo), "v"(hi));
    return r;
}

// Prep: W [128][64] f32 -> per-lane B-fragment image in d_ws (bf16).
// dst = w*2048 + l*32 + kc*8 + j  <->  c = w*16 + (l&15), f = kc*32 + (l>>4)*8 + j.
__global__ __launch_bounds__(256)
void prep_w(const float* __restrict__ W, unsigned short* __restrict__ wt) {
    const int dst = blockIdx.x * 256 + threadIdx.x;   // 8192 total
    const int j  = dst & 7;
    const int kc = (dst >> 3) & 3;
    const int l  = (dst >> 5) & 63;
    const int w  = dst >> 11;
    const int c  = w * 16 + (l & 15);
    const int f  = kc * 32 + (l >> 4) * 8 + j;
    wt[dst] = f2bf(W[f * 64 + c]);
}

__global__ __launch_bounds__(BLK, 4)
void gat_kernel(const float* __restrict__ x,
                const unsigned short* __restrict__ wt_ws,
                const float* __restrict__ a,
                float* __restrict__ out)
{
    __shared__ __align__(16) char smem[LDS_BYTES];

    const int t  = threadIdx.x;
    const int w  = t >> 6;    // wave -> col-tile
    const int l  = t & 63;
    const int lr = l & 15;    // A-row / B-col within tile
    const int lk = l >> 4;    // k sub-block (8 contiguous k)

    // B fragments FIRST so they are oldest in vmcnt order (4 x 16B, L2-hit)
    bf16x8 bfrag[4];
    {
        const bf16x8* wp = reinterpret_cast<const bf16x8*>(wt_ws + w * 2048 + l * 32);
#pragma unroll
        for (int kc = 0; kc < 4; ++kc) bfrag[kc] = wp[kc];
    }

    // ---- phase A: async DMA x -> LDS (fp32, swizzle via per-lane SOURCE addr) ----
    // issue j: wave w, lane l covers row j*8 + w*2 + (l>>5), 16B-unit (l&31)^(row&7).
    // LDS dest is linear (wave-uniform base + lane*16): slot row*32 + u holds
    // global unit u^(row&7)  =>  read side XORs the same way. row&7 is j-invariant.
    {
        const int rsub = w * 2 + (l >> 5);                 // 0..7 (== row&7)
        const int unit = (l & 31) ^ rsub;
        const char* gsrc = reinterpret_cast<const char*>(x)
                         + (size_t)blockIdx.x * (ROWS * Fc * 4)
                         + rsub * 512 + unit * 16;
#pragma unroll
        for (int j = 0; j < 6; ++j)
            __builtin_amdgcn_global_load_lds(
                (const __attribute__((address_space(1))) void*)(gsrc + j * 4096),
                (__attribute__((address_space(3))) void*)(smem + j * 4096 + w * 1024),
                16, 0, 0);
        // pin: gloads j0..5 (+bfrag) issue before j6..9 so vmcnt counting is exact
        __builtin_amdgcn_sched_barrier(0);
#pragma unroll
        for (int j = 6; j < 10; ++j)
            __builtin_amdgcn_global_load_lds(
                (const __attribute__((address_space(1))) void*)(gsrc + j * 4096),
                (__attribute__((address_space(3))) void*)(smem + j * 4096 + w * 1024),
                16, 0, 0);
    }

    f32x4 acc[MT];
#pragma unroll
    for (int m = 0; m < MT; ++m) acc[m] = (f32x4){0.f, 0.f, 0.f, 0.f};

    // ---- phase B part 1: rows 0..47 ready when my oldest 10 vmem are done ----
    asm volatile("s_waitcnt vmcnt(4)" ::: "memory");
    __builtin_amdgcn_s_barrier();
    __builtin_amdgcn_sched_barrier(0);

    const int rsw = lr & 7;
#pragma unroll
    for (int m = 0; m < 3; ++m) {
        const char* xrow = smem + (m * 16 + lr) * 512;
#pragma unroll
        for (int kc = 0; kc < 4; ++kc) {
            const int u0 = kc * 8 + lk * 2;
            const f32x4 p0 = *reinterpret_cast<const f32x4*>(xrow + ((u0)     ^ rsw) * 16);
            const f32x4 p1 = *reinterpret_cast<const f32x4*>(xrow + ((u0 + 1) ^ rsw) * 16);
            union { unsigned u[4]; bf16x8 v; } af;
            af.u[0] = cvtpk(p0[0], p0[1]);
            af.u[1] = cvtpk(p0[2], p0[3]);
            af.u[2] = cvtpk(p1[0], p1[1]);
            af.u[3] = cvtpk(p1[2], p1[3]);
            acc[m] = __builtin_amdgcn_mfma_f32_16x16x32_bf16(af.v, bfrag[kc], acc[m], 0, 0, 0);
        }
    }

    // ---- phase B part 2: rows 48..79 ----
    asm volatile("s_waitcnt vmcnt(0)" ::: "memory");
    __builtin_amdgcn_s_barrier();
    __builtin_amdgcn_sched_barrier(0);

#pragma unroll
    for (int m = 3; m < MT; ++m) {
        const char* xrow = smem + (m * 16 + lr) * 512;
#pragma unroll
        for (int kc = 0; kc < 4; ++kc) {
            const int u0 = kc * 8 + lk * 2;
            const f32x4 p0 = *reinterpret_cast<const f32x4*>(xrow + ((u0)     ^ rsw) * 16);
            const f32x4 p1 = *reinterpret_cast<const f32x4*>(xrow + ((u0 + 1) ^ rsw) * 16);
            union { unsigned u[4]; bf16x8 v; } af;
            af.u[0] = cvtpk(p0[0], p0[1]);
            af.u[1] = cvtpk(p0[2], p0[3]);
            af.u[2] = cvtpk(p1[0], p1[1]);
            af.u[3] = cvtpk(p1[2], p1[3]);
            acc[m] = __builtin_amdgcn_mfma_f32_16x16x32_bf16(af.v, bfrag[kc], acc[m], 0, 0, 0);
        }
    }

    // all x reads consumed -> safe to alias hw over the x region
    asm volatile("s_waitcnt lgkmcnt(0)" ::: "memory");
    __builtin_amdgcn_s_barrier();
    __builtin_amdgcn_sched_barrier(0);

    // ---- phase C: acc -> hw LDS [80][68] f32 (D-frag: row = lk*4+r, col = lr) ----
    {
        float* hw = reinterpret_cast<float*>(smem);
        const int col = w * 16 + lr;
#pragma unroll
        for (int m = 0; m < MT; ++m) {
            const int rbase = m * 16 + lk * 4;
#pragma unroll
            for (int r = 0; r < 4; ++r)
                hw[(rbase + r) * 68 + col] = acc[m][r];
        }
    }
    __syncthreads();

    // ---- phase D: online softmax over K=10 + leaky relu, thread = (node, head) ----
    if (t < NPB * Hc) {   // 128 active
        const int h  = t & 15;
        const int ln = t >> 4;
        const float ar0 = a[h];
        const float ar1 = a[16 + h];
        const float ar2 = a[32 + h];
        const float ar3 = a[48 + h];
        const float* hwb = reinterpret_cast<const float*>(smem) + (ln * Kc) * 68 + h * 4;

        float mx = -1e30f, lsum = 0.f;
        float o0 = 0.f, o1 = 0.f, o2 = 0.f, o3 = 0.f;
#pragma unroll
        for (int k = 0; k < Kc; ++k) {
            const float4 hv = *reinterpret_cast<const float4*>(hwb + k * 68);
            const float lg = fmaf(hv.x, ar0, fmaf(hv.y, ar1, fmaf(hv.z, ar2, hv.w * ar3)));
            const float mn = fmaxf(mx, lg);
            const float s  = __expf(mx - mn);
            const float p  = __expf(lg - mn);
            mx = mn;
            lsum = fmaf(lsum, s, p);
            o0 = fmaf(o0, s, p * hv.x);
            o1 = fmaf(o1, s, p * hv.y);
            o2 = fmaf(o2, s, p * hv.z);
            o3 = fmaf(o3, s, p * hv.w);
        }
        const float inv = 1.f / lsum;
        o0 *= inv; o1 *= inv; o2 *= inv; o3 *= inv;
        o0 = fmaxf(o0, 0.2f * o0);   // leaky_relu slope 0.2
        o1 = fmaxf(o1, 0.2f * o1);
        o2 = fmaxf(o2, 0.2f * o2);
        o3 = fmaxf(o3, 0.2f * o3);
        float* ol = reinterpret_cast<float*>(smem + OL_OFF);
        *reinterpret_cast<float4*>(ol + ln * 68 + h * 4) = make_float4(o0, o1, o2, o3);
    }
    __syncthreads();

    // ---- phase E: store transposed [B, 64, N], coalesced float4 ----
    if (t < 128) {
        const float* ol = reinterpret_cast<const float*>(smem + OL_OFF);
        const int c  = t >> 1;   // channel 0..63
        const int nq = t & 1;    // node quad 0..1
        const int nb = blockIdx.x * NPB;
        const int b  = nb / Nc;
        const int n0 = nb - b * Nc;
        float4 v;
        v.x = ol[(nq * 4 + 0) * 68 + c];
        v.y = ol[(nq * 4 + 1) * 68 + c];
        v.z = ol[(nq * 4 + 2) * 68 + c];
        v.w = ol[(nq * 4 + 3) * 68 + c];
        *reinterpret_cast<float4*>(out + ((size_t)b * Cc + c) * Nc + n0 + nq * 4) = v;
    }
}

extern "C" void kernel_launch(void* const* d_in, const int* in_sizes, int n_in,
                              void* d_out, int out_size, void* d_ws, size_t ws_size,
                              hipStream_t stream) {
    const float* x = (const float*)d_in[0];
    const float* W = (const float*)d_in[1];
    const float* a = (const float*)d_in[2];
    float* out = (float*)d_out;
    unsigned short* wt = (unsigned short*)d_ws;   // 16 KB used

    prep_w<<<32, 256, 0, stream>>>(W, wt);
    gat_kernel<<<NTILES, BLK, 0, stream>>>(x, wt, a, out);
}